// Round 2
// baseline (5759.706 us; speedup 1.0000x reference)
//
#include <hip/hip_runtime.h>

#define NA 10000
#define NE 320000
#define CHUNK 16

__device__ __forceinline__ float silu_f(float v) { return v / (1.0f + __expf(-v)); }

// ---------------- init: q=emb[Z], mu=0, Eat=e_field[idx_m], zero counts/cursor ----
__global__ __launch_bounds__(256) void k_init(
    const int* __restrict__ Z, const int* __restrict__ idx_m,
    const float* __restrict__ emb, const float* __restrict__ e_field,
    float* __restrict__ q, float* __restrict__ mu,
    float* __restrict__ Eat, int* __restrict__ counts, int* __restrict__ cursor)
{
    int gid = blockIdx.x * 256 + threadIdx.x;
    if (gid < NA * 384) mu[gid] = 0.0f;
    if (gid < NA * 128) {
        int i = gid >> 7, f = gid & 127;
        q[gid] = emb[Z[i] * 128 + f];
    }
    if (gid < NA * 3) {
        int i = gid / 3, d = gid - i * 3;
        Eat[gid] = e_field[idx_m[i] * 3 + d];
    }
    if (gid < NA) { counts[gid] = 0; cursor[gid] = 0; }
}

// ---------------- histogram idx_i ----------------------------------------------
__global__ __launch_bounds__(256) void k_count(
    const int* __restrict__ idx_i, int* __restrict__ counts)
{
    int e = blockIdx.x * 256 + threadIdx.x;
    if (e < NE) atomicAdd(&counts[idx_i[e]], 1);
}

// ---------------- exclusive scan of counts -> rowptr (single block) ------------
__global__ __launch_bounds__(256) void k_scan(const int* __restrict__ counts,
                                              int* __restrict__ rowptr)
{
    __shared__ int part[256];
    int tid = threadIdx.x;
    const int CH = (NA + 255) / 256;  // 40
    int base = tid * CH;
    int s = 0;
    for (int i2 = 0; i2 < CH; i2++) {
        int idx = base + i2;
        if (idx < NA) s += counts[idx];
    }
    part[tid] = s;
    __syncthreads();
    for (int ofs = 1; ofs < 256; ofs <<= 1) {
        int v = part[tid];
        int add = (tid >= ofs) ? part[tid - ofs] : 0;
        __syncthreads();
        part[tid] = v + add;
        __syncthreads();
    }
    int run = (tid > 0) ? part[tid - 1] : 0;
    for (int i2 = 0; i2 < CH; i2++) {
        int idx = base + i2;
        if (idx < NA) { rowptr[idx] = run; run += counts[idx]; }
        else if (idx == NA) rowptr[NA] = run;
    }
}

// ---------------- geometry + scatter into CSR order ----------------------------
// Writes phi*fcut (20), float4(dir.xyz, fcut), idx_j, row — all at sorted pos.
__global__ __launch_bounds__(256) void k_geom_scatter(
    const float* __restrict__ r_ij, const int* __restrict__ idx_i,
    const int* __restrict__ idx_j, const int* __restrict__ rowptr,
    int* __restrict__ cursor, float* __restrict__ phi_s,
    float4* __restrict__ df_s, int* __restrict__ j_s, int* __restrict__ row_s)
{
    int e = blockIdx.x * 256 + threadIdx.x;
    if (e >= NE) return;
    float x = r_ij[e*3+0], y = r_ij[e*3+1], z = r_ij[e*3+2];
    float d = sqrtf(x*x + y*y + z*z);
    float inv = 1.0f / d;
    float fc = (d < 5.0f) ? 0.5f * (__cosf(d * 0.628318530717958648f) + 1.0f) : 0.0f;
    int i = idx_i[e];
    int pos = rowptr[i] + atomicAdd(&cursor[i], 1);
    float4 dv; dv.x = x*inv; dv.y = y*inv; dv.z = z*inv; dv.w = fc;
    df_s[pos] = dv;
    j_s[pos] = idx_j[e];
    row_s[pos] = i;
    const float invw = 19.0f / 5.0f;
    float ph[20];
    #pragma unroll
    for (int k = 0; k < 20; k++) {
        float off = (5.0f / 19.0f) * (float)k;
        float u = (d - off) * invw;
        ph[k] = __expf(-0.5f * u * u) * fc;   // fcut folded in
    }
    #pragma unroll
    for (int c = 0; c < 5; c++) {
        float4 pv; pv.x = ph[c*4]; pv.y = ph[c*4+1]; pv.z = ph[c*4+2]; pv.w = ph[c*4+3];
        *(float4*)(phi_s + (size_t)pos*20 + c*4) = pv;
    }
}

// ---------------- mu copy (mu_nxt = mu_cur) ------------------------------------
__global__ __launch_bounds__(256) void k_copy(
    const float4* __restrict__ src, float4* __restrict__ dst)
{
    int gid = blockIdx.x * 256 + threadIdx.x;
    if (gid < NA * 96) dst[gid] = src[gid];
}

// ---------------- generic fp32 GEMM: C = act(A[M,K] @ W[K,N] + b) --------------
template<int ACT>
__global__ __launch_bounds__(256) void k_gemm(
    const float* __restrict__ A, const float* __restrict__ W,
    const float* __restrict__ bias, float* __restrict__ C,
    int M, int K, int N)
{
    __shared__ float As[16 * 68];
    __shared__ float Ws[16 * 68];
    int i0 = blockIdx.x * 64;
    int n0 = blockIdx.y * 64;
    int tid = threadIdx.x;
    int ty = tid >> 4, tx = tid & 15;
    int ar = tid >> 2;
    int ac = (tid & 3) << 2;
    int wr = tid >> 4;
    int wc = (tid & 15) << 2;
    float acc[4][4] = {};
    for (int k0 = 0; k0 < K; k0 += 16) {
        float4 av;
        if (i0 + ar < M) av = *(const float4*)(A + (i0 + ar) * K + k0 + ac);
        else { av.x = av.y = av.z = av.w = 0.0f; }
        float4 wv = *(const float4*)(W + (k0 + wr) * N + n0 + wc);
        __syncthreads();
        As[(ac+0)*68 + ar] = av.x;
        As[(ac+1)*68 + ar] = av.y;
        As[(ac+2)*68 + ar] = av.z;
        As[(ac+3)*68 + ar] = av.w;
        *(float4*)(Ws + wr*68 + wc) = wv;
        __syncthreads();
        #pragma unroll
        for (int k = 0; k < 16; k++) {
            float4 a = *(const float4*)(As + k*68 + ty*4);
            float4 w = *(const float4*)(Ws + k*68 + tx*4);
            acc[0][0] = fmaf(a.x, w.x, acc[0][0]);
            acc[0][1] = fmaf(a.x, w.y, acc[0][1]);
            acc[0][2] = fmaf(a.x, w.z, acc[0][2]);
            acc[0][3] = fmaf(a.x, w.w, acc[0][3]);
            acc[1][0] = fmaf(a.y, w.x, acc[1][0]);
            acc[1][1] = fmaf(a.y, w.y, acc[1][1]);
            acc[1][2] = fmaf(a.y, w.z, acc[1][2]);
            acc[1][3] = fmaf(a.y, w.w, acc[1][3]);
            acc[2][0] = fmaf(a.z, w.x, acc[2][0]);
            acc[2][1] = fmaf(a.z, w.y, acc[2][1]);
            acc[2][2] = fmaf(a.z, w.z, acc[2][2]);
            acc[2][3] = fmaf(a.z, w.w, acc[2][3]);
            acc[3][0] = fmaf(a.w, w.x, acc[3][0]);
            acc[3][1] = fmaf(a.w, w.y, acc[3][1]);
            acc[3][2] = fmaf(a.w, w.z, acc[3][2]);
            acc[3][3] = fmaf(a.w, w.w, acc[3][3]);
        }
    }
    float4 bv; bv.x = bv.y = bv.z = bv.w = 0.0f;
    if (bias) bv = *(const float4*)(bias + n0 + wc);
    #pragma unroll
    for (int r = 0; r < 4; r++) {
        int i = i0 + ty*4 + r;
        if (i < M) {
            float4 o;
            o.x = acc[r][0] + bv.x; o.y = acc[r][1] + bv.y;
            o.z = acc[r][2] + bv.z; o.w = acc[r][3] + bv.w;
            if (ACT) { o.x = silu_f(o.x); o.y = silu_f(o.y); o.z = silu_f(o.z); o.w = silu_f(o.w); }
            *(float4*)(C + i * N + n0 + tx*4) = o;
        }
    }
}

// ---------------- edge aggregation: CSR-chunked segmented reduction ------------
// One wave per CHUNK contiguous CSR positions. Lane owns features lane+c*64.
// Rows are non-decreasing within a chunk; flush accumulators on row change
// (atomicAdd). Filter dot fused (W staged in LDS). Batch of 2 edges for ILP.
__global__ __launch_bounds__(256, 4) void k_edge2(
    int t, const float* __restrict__ phi_s, const float4* __restrict__ df_s,
    const int* __restrict__ j_s, const int* __restrict__ row_s,
    const float* __restrict__ x, const float* __restrict__ mu_in,
    const float* __restrict__ filt_W, const float* __restrict__ filt_b,
    float* __restrict__ q, float* __restrict__ mu_out)
{
    __shared__ float wS[20 * 384];
    __shared__ float bS[384];
    const float* Wsl = filt_W + t * 1152 * 0 + t * 384;   // filt_W[k][t*384 + f], row stride 1152
    for (int i = threadIdx.x; i < 20 * 384; i += 256) {
        int k = i / 384, f = i - k * 384;
        wS[i] = Wsl[k * 1152 + f];
    }
    for (int i = threadIdx.x; i < 384; i += 256) bS[i] = filt_b[t * 384 + i];
    __syncthreads();

    int lane = threadIdx.x & 63;
    int wid = blockIdx.x * 4 + (threadIdx.x >> 6);
    int p0 = wid * CHUNK;                     // NE % (CHUNK*4) == 0

    float b2[6];
    #pragma unroll
    for (int c = 0; c < 6; c++) b2[c] = bS[lane + c*64];

    float acc[8] = {};   // dq0,dq1, dmu[0][0],dmu[0][1], dmu[1][*], dmu[2][*]
    int cur_row = row_s[p0];

    for (int pb = 0; pb < CHUNK; pb += 2) {
        int p = p0 + pb;
        int r0 = row_s[p],   r1 = row_s[p+1];
        int j0 = j_s[p],     j1 = j_s[p+1];
        float4 d0 = df_s[p], d1 = df_s[p+1];
        float ph0[20], ph1[20];
        #pragma unroll
        for (int c5 = 0; c5 < 5; c5++) {
            *(float4*)(ph0 + c5*4) = *(const float4*)(phi_s + (size_t)p*20 + c5*4);
            *(float4*)(ph1 + c5*4) = *(const float4*)(phi_s + (size_t)(p+1)*20 + c5*4);
        }
        float x0[6], x1[6], m0[6], m1[6];
        #pragma unroll
        for (int c = 0; c < 6; c++) {
            x0[c] = x[(size_t)j0*384 + lane + c*64];
            x1[c] = x[(size_t)j1*384 + lane + c*64];
        }
        #pragma unroll
        for (int d = 0; d < 3; d++) {
            m0[d*2]   = mu_in[((size_t)j0*3 + d)*128 + lane];
            m0[d*2+1] = mu_in[((size_t)j0*3 + d)*128 + lane + 64];
            m1[d*2]   = mu_in[((size_t)j1*3 + d)*128 + lane];
            m1[d*2+1] = mu_in[((size_t)j1*3 + d)*128 + lane + 64];
        }
        float dot0[6], dot1[6];
        #pragma unroll
        for (int c = 0; c < 6; c++) { dot0[c] = d0.w * b2[c]; dot1[c] = d1.w * b2[c]; }
        #pragma unroll
        for (int k = 0; k < 20; k++) {
            float p0v = ph0[k], p1v = ph1[k];
            #pragma unroll
            for (int c = 0; c < 6; c++) {
                float wv = wS[k*384 + lane + c*64];
                dot0[c] = fmaf(p0v, wv, dot0[c]);
                dot1[c] = fmaf(p1v, wv, dot1[c]);
            }
        }
        // ---- edge 0 ----
        if (r0 != cur_row) {
            atomicAdd(&q[(size_t)cur_row*128 + lane],      acc[0]);
            atomicAdd(&q[(size_t)cur_row*128 + lane + 64], acc[1]);
            #pragma unroll
            for (int d = 0; d < 3; d++) {
                atomicAdd(&mu_out[((size_t)cur_row*3 + d)*128 + lane],      acc[2 + d*2]);
                atomicAdd(&mu_out[((size_t)cur_row*3 + d)*128 + lane + 64], acc[3 + d*2]);
            }
            #pragma unroll
            for (int a = 0; a < 8; a++) acc[a] = 0.0f;
            cur_row = r0;
        }
        {
            float xx[6];
            #pragma unroll
            for (int c = 0; c < 6; c++) xx[c] = dot0[c] * x0[c];
            acc[0] += xx[0]; acc[1] += xx[1];
            float dr[3] = {d0.x, d0.y, d0.z};
            #pragma unroll
            for (int d = 0; d < 3; d++) {
                acc[2 + d*2] += xx[2]*dr[d] + xx[4]*m0[d*2];
                acc[3 + d*2] += xx[3]*dr[d] + xx[5]*m0[d*2+1];
            }
        }
        // ---- edge 1 ----
        if (r1 != cur_row) {
            atomicAdd(&q[(size_t)cur_row*128 + lane],      acc[0]);
            atomicAdd(&q[(size_t)cur_row*128 + lane + 64], acc[1]);
            #pragma unroll
            for (int d = 0; d < 3; d++) {
                atomicAdd(&mu_out[((size_t)cur_row*3 + d)*128 + lane],      acc[2 + d*2]);
                atomicAdd(&mu_out[((size_t)cur_row*3 + d)*128 + lane + 64], acc[3 + d*2]);
            }
            #pragma unroll
            for (int a = 0; a < 8; a++) acc[a] = 0.0f;
            cur_row = r1;
        }
        {
            float xx[6];
            #pragma unroll
            for (int c = 0; c < 6; c++) xx[c] = dot1[c] * x1[c];
            acc[0] += xx[0]; acc[1] += xx[1];
            float dr[3] = {d1.x, d1.y, d1.z};
            #pragma unroll
            for (int d = 0; d < 3; d++) {
                acc[2 + d*2] += xx[2]*dr[d] + xx[4]*m1[d*2];
                acc[3 + d*2] += xx[3]*dr[d] + xx[5]*m1[d*2+1];
            }
        }
    }
    // final flush
    atomicAdd(&q[(size_t)cur_row*128 + lane],      acc[0]);
    atomicAdd(&q[(size_t)cur_row*128 + lane + 64], acc[1]);
    #pragma unroll
    for (int d = 0; d < 3; d++) {
        atomicAdd(&mu_out[((size_t)cur_row*3 + d)*128 + lane],      acc[2 + d*2]);
        atomicAdd(&mu_out[((size_t)cur_row*3 + d)*128 + lane + 64], acc[3 + d*2]);
    }
}

// ---------------- field interaction elementwise update -------------------------
__global__ __launch_bounds__(256) void k_field(
    const float* __restrict__ a_s, const float* __restrict__ av,
    const float* __restrict__ Eat, float* __restrict__ mu)
{
    int gid = blockIdx.x * 256 + threadIdx.x;
    if (gid >= NA * 128) return;
    int i = gid >> 7, f = gid & 127;
    float E0 = Eat[i*3+0], E1 = Eat[i*3+1], E2 = Eat[i*3+2];
    float a0 = av[(i*3+0)*128+f], a1 = av[(i*3+1)*128+f], a2 = av[(i*3+2)*128+f];
    float dot = a0*E0 + a1*E1 + a2*E2;
    float s = a_s[gid];
    mu[(i*3+0)*128+f] += s*E0 - dot*a0;
    mu[(i*3+1)*128+f] += s*E1 - dot*a1;
    mu[(i*3+2)*128+f] += s*E2 - dot*a2;
}

// ---------------- mixing: mu_Vn and ctx = [q, mu_Vn] ---------------------------
__global__ __launch_bounds__(256) void k_mixnorm(
    const float* __restrict__ q, const float* __restrict__ mumix,
    float* __restrict__ ctx)
{
    int gid = blockIdx.x * 256 + threadIdx.x;
    if (gid >= NA * 128) return;
    int i = gid >> 7, f = gid & 127;
    float v0 = mumix[(i*3+0)*256+f], v1 = mumix[(i*3+1)*256+f], v2 = mumix[(i*3+2)*256+f];
    float vn = sqrtf(v0*v0 + v1*v1 + v2*v2 + 1e-8f);
    ctx[i*256 + f]       = q[gid];
    ctx[i*256 + 128 + f] = vn;
}

// ---------------- mixing final update ------------------------------------------
__global__ __launch_bounds__(256) void k_mixupd(
    const float* __restrict__ y, const float* __restrict__ mumix,
    float* __restrict__ q, float* __restrict__ mu)
{
    int gid = blockIdx.x * 256 + threadIdx.x;
    if (gid >= NA * 128) return;
    int i = gid >> 7, f = gid & 127;
    float yq  = y[i*384 + f];
    float ym  = y[i*384 + 128 + f];
    float yqm = y[i*384 + 256 + f];
    float sdot = 0.f;
    #pragma unroll
    for (int d = 0; d < 3; d++)
        sdot += mumix[(i*3+d)*256 + f] * mumix[(i*3+d)*256 + 128 + f];
    q[gid] += yq + yqm * sdot;
    #pragma unroll
    for (int d = 0; d < 3; d++)
        mu[(i*3+d)*128 + f] += ym * mumix[(i*3+d)*256 + 128 + f];
}

// ---------------- pack output [N,4,128] = [q, mu] -------------------------------
__global__ __launch_bounds__(256) void k_pack(
    const float* __restrict__ q, const float* __restrict__ mu,
    float* __restrict__ out)
{
    int gid = blockIdx.x * 256 + threadIdx.x;
    if (gid >= NA * 512) return;
    int i = gid >> 9, c = gid & 511;
    out[gid] = (c < 128) ? q[i*128 + c] : mu[i*384 + (c - 128)];
}

extern "C" void kernel_launch(void* const* d_in, const int* in_sizes, int n_in,
                              void* d_out, int out_size, void* d_ws, size_t ws_size,
                              hipStream_t stream)
{
    const int*   Z       = (const int*)d_in[0];
    const float* r_ij    = (const float*)d_in[1];
    const int*   idx_i   = (const int*)d_in[2];
    const int*   idx_j   = (const int*)d_in[3];
    const int*   idx_m   = (const int*)d_in[4];
    const float* e_field = (const float*)d_in[5];
    const float* emb     = (const float*)d_in[6];
    const float* filt_W  = (const float*)d_in[7];
    const float* filt_b  = (const float*)d_in[8];
    const float* iW1     = (const float*)d_in[9];
    const float* ib1     = (const float*)d_in[10];
    const float* iW2     = (const float*)d_in[11];
    const float* ib2     = (const float*)d_in[12];
    const float* sW1     = (const float*)d_in[13];
    const float* sb1     = (const float*)d_in[14];
    const float* sW2     = (const float*)d_in[15];
    const float* sb2     = (const float*)d_in[16];
    const float* vW      = (const float*)d_in[17];
    const float* mmW     = (const float*)d_in[18];
    const float* mW1     = (const float*)d_in[19];
    const float* mb1     = (const float*)d_in[20];
    const float* mW2     = (const float*)d_in[21];
    const float* mb2     = (const float*)d_in[22];
    float* out = (float*)d_out;

    float* base = (float*)d_ws;
    size_t off = 0;
    auto alloc = [&](size_t n) { float* p = base + off; off += (n + 255) & ~(size_t)255; return p; };
    float* q     = alloc((size_t)NA*128);
    float* mu_a  = alloc((size_t)NA*384);
    float* mu_b  = alloc((size_t)NA*384);
    float* h     = alloc((size_t)NA*128);
    float* a_s   = alloc((size_t)NA*128);
    float* s384  = alloc((size_t)NA*384);
    float* mumix = alloc((size_t)NA*768);
    float* ctx   = alloc((size_t)NA*256);
    float* Eat   = alloc((size_t)NA*3);
    float* phi_s = alloc((size_t)NE*20);
    float4* df_s = (float4*)alloc((size_t)NE*4);
    int* rowptr  = (int*)alloc(NA + 1);
    int* counts  = (int*)alloc(NA);
    int* cursor  = (int*)alloc(NA);
    int* j_s     = (int*)alloc(NE);
    int* row_s   = (int*)alloc(NE);
    (void)ws_size; (void)in_sizes; (void)n_in; (void)out_size;

    k_init        <<<(NA*384 + 255)/256, 256, 0, stream>>>(Z, idx_m, emb, e_field, q, mu_a, Eat, counts, cursor);
    k_count       <<<(NE + 255)/256,     256, 0, stream>>>(idx_i, counts);
    k_scan        <<<1,                  256, 0, stream>>>(counts, rowptr);
    k_geom_scatter<<<(NE + 255)/256,     256, 0, stream>>>(r_ij, idx_i, idx_j, rowptr, cursor,
                                                           phi_s, df_s, j_s, row_s);

    const int GN  = (NA + 63) / 64;      // 157
    const int GN3 = (NA*3 + 63) / 64;    // 469
    float* mu_cur = mu_a;
    float* mu_nxt = mu_b;
    for (int t = 0; t < 3; t++) {
        // Interaction: x = silu(q@iW1+b1)@iW2+b2
        k_gemm<1><<<dim3(GN, 2), 256, 0, stream>>>(q, iW1 + t*128*128, ib1 + t*128, h,    NA, 128, 128);
        k_gemm<0><<<dim3(GN, 6), 256, 0, stream>>>(h, iW2 + t*128*384, ib2 + t*384, s384, NA, 128, 384);
        // edge message passing: q += dq (atomic); mu_nxt = mu_cur + dmu (copy + atomic)
        k_copy <<<(NA*96 + 255)/256, 256, 0, stream>>>((const float4*)mu_cur, (float4*)mu_nxt);
        k_edge2<<<NE/(CHUNK*4), 256, 0, stream>>>(t, phi_s, df_s, j_s, row_s, s384,
                                                  mu_cur, filt_W, filt_b, q, mu_nxt);
        { float* tmp = mu_cur; mu_cur = mu_nxt; mu_nxt = tmp; }
        // FieldInteraction
        k_gemm<1><<<dim3(GN, 2),  256, 0, stream>>>(q,  sW1 + t*128*128, sb1 + t*128, h,    NA,   128, 128);
        k_gemm<0><<<dim3(GN, 2),  256, 0, stream>>>(h,  sW2 + t*128*128, sb2 + t*128, a_s,  NA,   128, 128);
        k_gemm<0><<<dim3(GN3, 2), 256, 0, stream>>>(mu_cur, vW + t*128*128, nullptr,  s384, NA*3, 128, 128);
        k_field<<<(NA*128 + 255)/256, 256, 0, stream>>>(a_s, s384, Eat, mu_cur);
        // Mixing
        k_gemm<0><<<dim3(GN3, 4), 256, 0, stream>>>(mu_cur, mmW + t*128*256, nullptr, mumix, NA*3, 128, 256);
        k_mixnorm<<<(NA*128 + 255)/256, 256, 0, stream>>>(q, mumix, ctx);
        k_gemm<1><<<dim3(GN, 2), 256, 0, stream>>>(ctx, mW1 + t*256*128, mb1 + t*128, h,    NA, 256, 128);
        k_gemm<0><<<dim3(GN, 6), 256, 0, stream>>>(h,   mW2 + t*128*384, mb2 + t*384, s384, NA, 128, 384);
        k_mixupd<<<(NA*128 + 255)/256, 256, 0, stream>>>(s384, mumix, q, mu_cur);
    }
    k_pack<<<(NA*512 + 255)/256, 256, 0, stream>>>(q, mu_cur, out);
}

// Round 3
// 1334.907 us; speedup vs baseline: 4.3147x; 4.3147x over previous
//
#include <hip/hip_runtime.h>

#define NA 10000
#define NE 320000

__device__ __forceinline__ float silu_f(float v) { return v / (1.0f + __expf(-v)); }

// ---------------- init: q=emb[Z], mu=0, Eat=e_field[idx_m], zero counts/cursor ----
__global__ __launch_bounds__(256) void k_init(
    const int* __restrict__ Z, const int* __restrict__ idx_m,
    const float* __restrict__ emb, const float* __restrict__ e_field,
    float* __restrict__ q, float* __restrict__ mu,
    float* __restrict__ Eat, int* __restrict__ counts, int* __restrict__ cursor)
{
    int gid = blockIdx.x * 256 + threadIdx.x;
    if (gid < NA * 384) mu[gid] = 0.0f;
    if (gid < NA * 128) {
        int i = gid >> 7, f = gid & 127;
        q[gid] = emb[Z[i] * 128 + f];
    }
    if (gid < NA * 3) {
        int i = gid / 3, d = gid - i * 3;
        Eat[gid] = e_field[idx_m[i] * 3 + d];
    }
    if (gid < NA) { counts[gid] = 0; cursor[gid] = 0; }
}

// ---------------- histogram idx_i ----------------------------------------------
__global__ __launch_bounds__(256) void k_count(
    const int* __restrict__ idx_i, int* __restrict__ counts)
{
    int e = blockIdx.x * 256 + threadIdx.x;
    if (e < NE) atomicAdd(&counts[idx_i[e]], 1);
}

// ---------------- exclusive scan of counts -> rowptr (single block) ------------
__global__ __launch_bounds__(256) void k_scan(const int* __restrict__ counts,
                                              int* __restrict__ rowptr)
{
    __shared__ int part[256];
    int tid = threadIdx.x;
    const int CH = (NA + 255) / 256;  // 40
    int base = tid * CH;
    int s = 0;
    for (int i2 = 0; i2 < CH; i2++) {
        int idx = base + i2;
        if (idx < NA) s += counts[idx];
    }
    part[tid] = s;
    __syncthreads();
    for (int ofs = 1; ofs < 256; ofs <<= 1) {
        int v = part[tid];
        int add = (tid >= ofs) ? part[tid - ofs] : 0;
        __syncthreads();
        part[tid] = v + add;
        __syncthreads();
    }
    int run = (tid > 0) ? part[tid - 1] : 0;
    for (int i2 = 0; i2 < CH; i2++) {
        int idx = base + i2;
        if (idx < NA) { rowptr[idx] = run; run += counts[idx]; }
        else if (idx == NA) rowptr[NA] = run;
    }
}

// ---------------- geometry + scatter into CSR order ----------------------------
// Writes phi*fcut (20), float4(dir.xyz, fcut), idx_j — all at CSR-sorted pos.
__global__ __launch_bounds__(256) void k_geom_scatter(
    const float* __restrict__ r_ij, const int* __restrict__ idx_i,
    const int* __restrict__ idx_j, const int* __restrict__ rowptr,
    int* __restrict__ cursor, float* __restrict__ phi_s,
    float4* __restrict__ df_s, int* __restrict__ j_s)
{
    int e = blockIdx.x * 256 + threadIdx.x;
    if (e >= NE) return;
    float x = r_ij[e*3+0], y = r_ij[e*3+1], z = r_ij[e*3+2];
    float d = sqrtf(x*x + y*y + z*z);
    float inv = 1.0f / d;
    float fc = (d < 5.0f) ? 0.5f * (__cosf(d * 0.628318530717958648f) + 1.0f) : 0.0f;
    int i = idx_i[e];
    int pos = rowptr[i] + atomicAdd(&cursor[i], 1);
    float4 dv; dv.x = x*inv; dv.y = y*inv; dv.z = z*inv; dv.w = fc;
    df_s[pos] = dv;
    j_s[pos] = idx_j[e];
    const float invw = 19.0f / 5.0f;
    float ph[20];
    #pragma unroll
    for (int k = 0; k < 20; k++) {
        float off = (5.0f / 19.0f) * (float)k;
        float u = (d - off) * invw;
        ph[k] = __expf(-0.5f * u * u) * fc;   // fcut folded in
    }
    #pragma unroll
    for (int c = 0; c < 5; c++) {
        float4 pv; pv.x = ph[c*4]; pv.y = ph[c*4+1]; pv.z = ph[c*4+2]; pv.w = ph[c*4+3];
        *(float4*)(phi_s + (size_t)pos*20 + c*4) = pv;
    }
}

// ---------------- generic fp32 GEMM: C = act(A[M,K] @ W[K,N] + b) --------------
template<int ACT>
__global__ __launch_bounds__(256) void k_gemm(
    const float* __restrict__ A, const float* __restrict__ W,
    const float* __restrict__ bias, float* __restrict__ C,
    int M, int K, int N)
{
    __shared__ float As[16 * 68];
    __shared__ float Ws[16 * 68];
    int i0 = blockIdx.x * 64;
    int n0 = blockIdx.y * 64;
    int tid = threadIdx.x;
    int ty = tid >> 4, tx = tid & 15;
    int ar = tid >> 2;
    int ac = (tid & 3) << 2;
    int wr = tid >> 4;
    int wc = (tid & 15) << 2;
    float acc[4][4] = {};
    for (int k0 = 0; k0 < K; k0 += 16) {
        float4 av;
        if (i0 + ar < M) av = *(const float4*)(A + (i0 + ar) * K + k0 + ac);
        else { av.x = av.y = av.z = av.w = 0.0f; }
        float4 wv = *(const float4*)(W + (k0 + wr) * N + n0 + wc);
        __syncthreads();
        As[(ac+0)*68 + ar] = av.x;
        As[(ac+1)*68 + ar] = av.y;
        As[(ac+2)*68 + ar] = av.z;
        As[(ac+3)*68 + ar] = av.w;
        *(float4*)(Ws + wr*68 + wc) = wv;
        __syncthreads();
        #pragma unroll
        for (int k = 0; k < 16; k++) {
            float4 a = *(const float4*)(As + k*68 + ty*4);
            float4 w = *(const float4*)(Ws + k*68 + tx*4);
            acc[0][0] = fmaf(a.x, w.x, acc[0][0]);
            acc[0][1] = fmaf(a.x, w.y, acc[0][1]);
            acc[0][2] = fmaf(a.x, w.z, acc[0][2]);
            acc[0][3] = fmaf(a.x, w.w, acc[0][3]);
            acc[1][0] = fmaf(a.y, w.x, acc[1][0]);
            acc[1][1] = fmaf(a.y, w.y, acc[1][1]);
            acc[1][2] = fmaf(a.y, w.z, acc[1][2]);
            acc[1][3] = fmaf(a.y, w.w, acc[1][3]);
            acc[2][0] = fmaf(a.z, w.x, acc[2][0]);
            acc[2][1] = fmaf(a.z, w.y, acc[2][1]);
            acc[2][2] = fmaf(a.z, w.z, acc[2][2]);
            acc[2][3] = fmaf(a.z, w.w, acc[2][3]);
            acc[3][0] = fmaf(a.w, w.x, acc[3][0]);
            acc[3][1] = fmaf(a.w, w.y, acc[3][1]);
            acc[3][2] = fmaf(a.w, w.z, acc[3][2]);
            acc[3][3] = fmaf(a.w, w.w, acc[3][3]);
        }
    }
    float4 bv; bv.x = bv.y = bv.z = bv.w = 0.0f;
    if (bias) bv = *(const float4*)(bias + n0 + wc);
    #pragma unroll
    for (int r = 0; r < 4; r++) {
        int i = i0 + ty*4 + r;
        if (i < M) {
            float4 o;
            o.x = acc[r][0] + bv.x; o.y = acc[r][1] + bv.y;
            o.z = acc[r][2] + bv.z; o.w = acc[r][3] + bv.w;
            if (ACT) { o.x = silu_f(o.x); o.y = silu_f(o.y); o.z = silu_f(o.z); o.w = silu_f(o.w); }
            *(float4*)(C + i * N + n0 + tx*4) = o;
        }
    }
}

// ---------------- edge aggregation: atom-centric, feature-split, no atomics ----
// Block = 4 waves = 2 atoms x 2 feature-halves. Wave (ia, h) owns features
// f = lane + h*64 and channels ch = {h, 2+h, 4+h} (dq / dmuR / dmumu).
// Filter weights held in 60 VGPRs per lane (no LDS). Edges read in CSR order.
__global__ __launch_bounds__(256, 3) void k_edge3(
    int t, const float* __restrict__ phi_s, const float4* __restrict__ df_s,
    const int* __restrict__ j_s, const int* __restrict__ rowptr,
    const float* __restrict__ x, const float* __restrict__ mu_in,
    const float* __restrict__ filt_W, const float* __restrict__ filt_b,
    float* __restrict__ q, float* __restrict__ mu_out)
{
    int lane = threadIdx.x & 63;
    int wv   = threadIdx.x >> 6;
    int ia   = blockIdx.x * 2 + (wv >> 1);
    int h    = wv & 1;
    int f    = lane + h * 64;

    float wreg[3][20];
    float b3[3];
    #pragma unroll
    for (int c = 0; c < 3; c++) {
        int col = t * 384 + (2*c + h) * 64 + lane;
        b3[c] = filt_b[col];
        #pragma unroll
        for (int k = 0; k < 20; k++)
            wreg[c][k] = filt_W[k * 1152 + col];
    }

    float accq = 0.0f, acc0 = 0.0f, acc1 = 0.0f, acc2 = 0.0f;
    int p0 = rowptr[ia], p1 = rowptr[ia + 1];
    int p = p0;
    for (; p + 2 <= p1; p += 2) {
        int j0 = j_s[p], j1 = j_s[p + 1];
        float4 d0 = df_s[p], d1 = df_s[p + 1];
        float dots0[3], dots1[3];
        #pragma unroll
        for (int c = 0; c < 3; c++) { dots0[c] = d0.w * b3[c]; dots1[c] = d1.w * b3[c]; }
        #pragma unroll
        for (int kq = 0; kq < 5; kq++) {
            float4 a0 = *(const float4*)(phi_s + (size_t)p * 20 + kq * 4);
            float4 a1 = *(const float4*)(phi_s + (size_t)(p + 1) * 20 + kq * 4);
            #pragma unroll
            for (int c = 0; c < 3; c++) {
                dots0[c] = fmaf(a0.x, wreg[c][kq*4+0], dots0[c]);
                dots0[c] = fmaf(a0.y, wreg[c][kq*4+1], dots0[c]);
                dots0[c] = fmaf(a0.z, wreg[c][kq*4+2], dots0[c]);
                dots0[c] = fmaf(a0.w, wreg[c][kq*4+3], dots0[c]);
                dots1[c] = fmaf(a1.x, wreg[c][kq*4+0], dots1[c]);
                dots1[c] = fmaf(a1.y, wreg[c][kq*4+1], dots1[c]);
                dots1[c] = fmaf(a1.z, wreg[c][kq*4+2], dots1[c]);
                dots1[c] = fmaf(a1.w, wreg[c][kq*4+3], dots1[c]);
            }
        }
        float xq0 = x[(size_t)j0*384 + h*64       + lane];
        float xr0 = x[(size_t)j0*384 + (2+h)*64   + lane];
        float xm0 = x[(size_t)j0*384 + (4+h)*64   + lane];
        float m00 = mu_in[((size_t)j0*3 + 0)*128 + f];
        float m01 = mu_in[((size_t)j0*3 + 1)*128 + f];
        float m02 = mu_in[((size_t)j0*3 + 2)*128 + f];
        float xq1 = x[(size_t)j1*384 + h*64       + lane];
        float xr1 = x[(size_t)j1*384 + (2+h)*64   + lane];
        float xm1 = x[(size_t)j1*384 + (4+h)*64   + lane];
        float m10 = mu_in[((size_t)j1*3 + 0)*128 + f];
        float m11 = mu_in[((size_t)j1*3 + 1)*128 + f];
        float m12 = mu_in[((size_t)j1*3 + 2)*128 + f];
        float xxq0 = dots0[0] * xq0, xxr0 = dots0[1] * xr0, xxm0 = dots0[2] * xm0;
        float xxq1 = dots1[0] * xq1, xxr1 = dots1[1] * xr1, xxm1 = dots1[2] * xm1;
        accq += xxq0 + xxq1;
        acc0 += xxr0*d0.x + xxm0*m00 + xxr1*d1.x + xxm1*m10;
        acc1 += xxr0*d0.y + xxm0*m01 + xxr1*d1.y + xxm1*m11;
        acc2 += xxr0*d0.z + xxm0*m02 + xxr1*d1.z + xxm1*m12;
    }
    if (p < p1) {
        int j0 = j_s[p];
        float4 d0 = df_s[p];
        float dots0[3];
        #pragma unroll
        for (int c = 0; c < 3; c++) dots0[c] = d0.w * b3[c];
        #pragma unroll
        for (int kq = 0; kq < 5; kq++) {
            float4 a0 = *(const float4*)(phi_s + (size_t)p * 20 + kq * 4);
            #pragma unroll
            for (int c = 0; c < 3; c++) {
                dots0[c] = fmaf(a0.x, wreg[c][kq*4+0], dots0[c]);
                dots0[c] = fmaf(a0.y, wreg[c][kq*4+1], dots0[c]);
                dots0[c] = fmaf(a0.z, wreg[c][kq*4+2], dots0[c]);
                dots0[c] = fmaf(a0.w, wreg[c][kq*4+3], dots0[c]);
            }
        }
        float xq0 = x[(size_t)j0*384 + h*64     + lane];
        float xr0 = x[(size_t)j0*384 + (2+h)*64 + lane];
        float xm0 = x[(size_t)j0*384 + (4+h)*64 + lane];
        float m00 = mu_in[((size_t)j0*3 + 0)*128 + f];
        float m01 = mu_in[((size_t)j0*3 + 1)*128 + f];
        float m02 = mu_in[((size_t)j0*3 + 2)*128 + f];
        float xxq0 = dots0[0] * xq0, xxr0 = dots0[1] * xr0, xxm0 = dots0[2] * xm0;
        accq += xxq0;
        acc0 += xxr0*d0.x + xxm0*m00;
        acc1 += xxr0*d0.y + xxm0*m01;
        acc2 += xxr0*d0.z + xxm0*m02;
    }
    q[(size_t)ia*128 + f] += accq;
    mu_out[((size_t)ia*3 + 0)*128 + f] = mu_in[((size_t)ia*3 + 0)*128 + f] + acc0;
    mu_out[((size_t)ia*3 + 1)*128 + f] = mu_in[((size_t)ia*3 + 1)*128 + f] + acc1;
    mu_out[((size_t)ia*3 + 2)*128 + f] = mu_in[((size_t)ia*3 + 2)*128 + f] + acc2;
}

// ---------------- field interaction elementwise update -------------------------
__global__ __launch_bounds__(256) void k_field(
    const float* __restrict__ a_s, const float* __restrict__ av,
    const float* __restrict__ Eat, float* __restrict__ mu)
{
    int gid = blockIdx.x * 256 + threadIdx.x;
    if (gid >= NA * 128) return;
    int i = gid >> 7, f = gid & 127;
    float E0 = Eat[i*3+0], E1 = Eat[i*3+1], E2 = Eat[i*3+2];
    float a0 = av[(i*3+0)*128+f], a1 = av[(i*3+1)*128+f], a2 = av[(i*3+2)*128+f];
    float dot = a0*E0 + a1*E1 + a2*E2;
    float s = a_s[gid];
    mu[(i*3+0)*128+f] += s*E0 - dot*a0;
    mu[(i*3+1)*128+f] += s*E1 - dot*a1;
    mu[(i*3+2)*128+f] += s*E2 - dot*a2;
}

// ---------------- mixing: mu_Vn and ctx = [q, mu_Vn] ---------------------------
__global__ __launch_bounds__(256) void k_mixnorm(
    const float* __restrict__ q, const float* __restrict__ mumix,
    float* __restrict__ ctx)
{
    int gid = blockIdx.x * 256 + threadIdx.x;
    if (gid >= NA * 128) return;
    int i = gid >> 7, f = gid & 127;
    float v0 = mumix[(i*3+0)*256+f], v1 = mumix[(i*3+1)*256+f], v2 = mumix[(i*3+2)*256+f];
    float vn = sqrtf(v0*v0 + v1*v1 + v2*v2 + 1e-8f);
    ctx[i*256 + f]       = q[gid];
    ctx[i*256 + 128 + f] = vn;
}

// ---------------- mixing final update ------------------------------------------
__global__ __launch_bounds__(256) void k_mixupd(
    const float* __restrict__ y, const float* __restrict__ mumix,
    float* __restrict__ q, float* __restrict__ mu)
{
    int gid = blockIdx.x * 256 + threadIdx.x;
    if (gid >= NA * 128) return;
    int i = gid >> 7, f = gid & 127;
    float yq  = y[i*384 + f];
    float ym  = y[i*384 + 128 + f];
    float yqm = y[i*384 + 256 + f];
    float sdot = 0.f;
    #pragma unroll
    for (int d = 0; d < 3; d++)
        sdot += mumix[(i*3+d)*256 + f] * mumix[(i*3+d)*256 + 128 + f];
    q[gid] += yq + yqm * sdot;
    #pragma unroll
    for (int d = 0; d < 3; d++)
        mu[(i*3+d)*128 + f] += ym * mumix[(i*3+d)*256 + 128 + f];
}

// ---------------- pack output [N,4,128] = [q, mu] -------------------------------
__global__ __launch_bounds__(256) void k_pack(
    const float* __restrict__ q, const float* __restrict__ mu,
    float* __restrict__ out)
{
    int gid = blockIdx.x * 256 + threadIdx.x;
    if (gid >= NA * 512) return;
    int i = gid >> 9, c = gid & 511;
    out[gid] = (c < 128) ? q[i*128 + c] : mu[i*384 + (c - 128)];
}

extern "C" void kernel_launch(void* const* d_in, const int* in_sizes, int n_in,
                              void* d_out, int out_size, void* d_ws, size_t ws_size,
                              hipStream_t stream)
{
    const int*   Z       = (const int*)d_in[0];
    const float* r_ij    = (const float*)d_in[1];
    const int*   idx_i   = (const int*)d_in[2];
    const int*   idx_j   = (const int*)d_in[3];
    const int*   idx_m   = (const int*)d_in[4];
    const float* e_field = (const float*)d_in[5];
    const float* emb     = (const float*)d_in[6];
    const float* filt_W  = (const float*)d_in[7];
    const float* filt_b  = (const float*)d_in[8];
    const float* iW1     = (const float*)d_in[9];
    const float* ib1     = (const float*)d_in[10];
    const float* iW2     = (const float*)d_in[11];
    const float* ib2     = (const float*)d_in[12];
    const float* sW1     = (const float*)d_in[13];
    const float* sb1     = (const float*)d_in[14];
    const float* sW2     = (const float*)d_in[15];
    const float* sb2     = (const float*)d_in[16];
    const float* vW      = (const float*)d_in[17];
    const float* mmW     = (const float*)d_in[18];
    const float* mW1     = (const float*)d_in[19];
    const float* mb1     = (const float*)d_in[20];
    const float* mW2     = (const float*)d_in[21];
    const float* mb2     = (const float*)d_in[22];
    float* out = (float*)d_out;

    float* base = (float*)d_ws;
    size_t off = 0;
    auto alloc = [&](size_t n) { float* p = base + off; off += (n + 255) & ~(size_t)255; return p; };
    float* q     = alloc((size_t)NA*128);
    float* mu_a  = alloc((size_t)NA*384);
    float* mu_b  = alloc((size_t)NA*384);
    float* h     = alloc((size_t)NA*128);
    float* a_s   = alloc((size_t)NA*128);
    float* s384  = alloc((size_t)NA*384);
    float* mumix = alloc((size_t)NA*768);
    float* ctx   = alloc((size_t)NA*256);
    float* Eat   = alloc((size_t)NA*3);
    float* phi_s = alloc((size_t)NE*20);
    float4* df_s = (float4*)alloc((size_t)NE*4);
    int* rowptr  = (int*)alloc(NA + 1);
    int* counts  = (int*)alloc(NA);
    int* cursor  = (int*)alloc(NA);
    int* j_s     = (int*)alloc(NE);
    (void)ws_size; (void)in_sizes; (void)n_in; (void)out_size;

    k_init        <<<(NA*384 + 255)/256, 256, 0, stream>>>(Z, idx_m, emb, e_field, q, mu_a, Eat, counts, cursor);
    k_count       <<<(NE + 255)/256,     256, 0, stream>>>(idx_i, counts);
    k_scan        <<<1,                  256, 0, stream>>>(counts, rowptr);
    k_geom_scatter<<<(NE + 255)/256,     256, 0, stream>>>(r_ij, idx_i, idx_j, rowptr, cursor,
                                                           phi_s, df_s, j_s);

    const int GN  = (NA + 63) / 64;      // 157
    const int GN3 = (NA*3 + 63) / 64;    // 469
    float* mu_cur = mu_a;
    float* mu_nxt = mu_b;
    for (int t = 0; t < 3; t++) {
        // Interaction: x = silu(q@iW1+b1)@iW2+b2
        k_gemm<1><<<dim3(GN, 2), 256, 0, stream>>>(q, iW1 + t*128*128, ib1 + t*128, h,    NA, 128, 128);
        k_gemm<0><<<dim3(GN, 6), 256, 0, stream>>>(h, iW2 + t*128*384, ib2 + t*384, s384, NA, 128, 384);
        // edge message passing: q += dq; mu_nxt = mu_cur + dmu (owner-exclusive, no atomics)
        k_edge3<<<NA/2, 256, 0, stream>>>(t, phi_s, df_s, j_s, rowptr, s384,
                                          mu_cur, filt_W, filt_b, q, mu_nxt);
        { float* tmp = mu_cur; mu_cur = mu_nxt; mu_nxt = tmp; }
        // FieldInteraction
        k_gemm<1><<<dim3(GN, 2),  256, 0, stream>>>(q,  sW1 + t*128*128, sb1 + t*128, h,    NA,   128, 128);
        k_gemm<0><<<dim3(GN, 2),  256, 0, stream>>>(h,  sW2 + t*128*128, sb2 + t*128, a_s,  NA,   128, 128);
        k_gemm<0><<<dim3(GN3, 2), 256, 0, stream>>>(mu_cur, vW + t*128*128, nullptr,  s384, NA*3, 128, 128);
        k_field<<<(NA*128 + 255)/256, 256, 0, stream>>>(a_s, s384, Eat, mu_cur);
        // Mixing
        k_gemm<0><<<dim3(GN3, 4), 256, 0, stream>>>(mu_cur, mmW + t*128*256, nullptr, mumix, NA*3, 128, 256);
        k_mixnorm<<<(NA*128 + 255)/256, 256, 0, stream>>>(q, mumix, ctx);
        k_gemm<1><<<dim3(GN, 2), 256, 0, stream>>>(ctx, mW1 + t*256*128, mb1 + t*128, h,    NA, 256, 128);
        k_gemm<0><<<dim3(GN, 6), 256, 0, stream>>>(h,   mW2 + t*128*384, mb2 + t*384, s384, NA, 128, 384);
        k_mixupd<<<(NA*128 + 255)/256, 256, 0, stream>>>(s384, mumix, q, mu_cur);
    }
    k_pack<<<(NA*512 + 255)/256, 256, 0, stream>>>(q, mu_cur, out);
}